// Round 4
// baseline (230.631 us; speedup 1.0000x reference)
//
#include <hip/hip_runtime.h>

typedef __attribute__((ext_vector_type(4))) int i32x4;

// ---------------------------------------------------------------------------
// Helpers
// ---------------------------------------------------------------------------
__device__ __forceinline__ void gload_lds16(const void* g, void* l) {
  // async global->LDS, 16B/lane. LDS dest must be wave-uniform base + lane*16.
  __builtin_amdgcn_global_load_lds((const __attribute__((address_space(1))) void*)g,
                                   (__attribute__((address_space(3))) void*)l,
                                   16, 0, 0);
}

#define BARRIER() __builtin_amdgcn_s_barrier()
#define LGKM0()   asm volatile("s_waitcnt lgkmcnt(0)" ::: "memory")
#define VMCNT2()  asm volatile("s_waitcnt vmcnt(2)" ::: "memory")

// ---------------------------------------------------------------------------
// Quantize f32 -> int8 (round-half-even like jnp.round, clamp to +-127)
// ---------------------------------------------------------------------------
__global__ void quant_i8_kernel(const float* __restrict__ in,
                                signed char* __restrict__ out,
                                const float* __restrict__ amax, int n4) {
  const float s = 127.0f / amax[0];
  int i = blockIdx.x * blockDim.x + threadIdx.x;
  const int stride = gridDim.x * blockDim.x;
  const float4* __restrict__ in4 = (const float4*)in;
  int* __restrict__ o4 = (int*)out;
  for (; i < n4; i += stride) {
    float4 v = in4[i];
    int q0 = (int)rintf(fminf(fmaxf(v.x * s, -127.0f), 127.0f));
    int q1 = (int)rintf(fminf(fmaxf(v.y * s, -127.0f), 127.0f));
    int q2 = (int)rintf(fminf(fmaxf(v.z * s, -127.0f), 127.0f));
    int q3 = (int)rintf(fminf(fmaxf(v.w * s, -127.0f), 127.0f));
    o4[i] = (q0 & 255) | ((q1 & 255) << 8) | ((q2 & 255) << 16) | ((q3 & 255) << 24);
  }
}

// ---------------------------------------------------------------------------
// 128x128-tile 4-phase int8 GEMM, 2 blocks/CU (64 KiB LDS, <=128 VGPR).
// out[N,M] = dequant(qx[N,K] . qw[M,K]^T) + bias
// 512 thr = 8 waves (2M x 4N), per-wave 64x32, mfma_i32_16x16x64_i8,
// BK=128 int8 (2 k-subtiles of 64), LDS = 2dbuf x (A,B) x [128][128B] = 64 KiB.
// Swizzle: 16B-chunk' = chunk ^ (row&7), applied to global SOURCE on staging
// (LDS dest linear, rule #21) and to the ds_read address. Proven 0-conflict.
// Counted-vmcnt gates: vmcnt(2) at end-P2 / end-P4 (never drain to 0 in loop).
// ---------------------------------------------------------------------------
__global__ __launch_bounds__(512, 4) void gemm_i8_4p(
    const signed char* __restrict__ qx,   // [N,K]
    const signed char* __restrict__ qw,   // [M,K]
    const float* __restrict__ bias,       // [M]
    const float* __restrict__ amax_x,
    const float* __restrict__ amax_w,
    float* __restrict__ out,              // [N,M]
    int N, int M, int K) {
  constexpr int BKB = 128;  // K bytes per tile

  __shared__ signed char lds[4][128 * 128];  // [A0,B0,A1,B1], 16 KiB each

  const int tid  = threadIdx.x;
  const int lane = tid & 63;
  const int wid  = tid >> 6;
  const int wm   = wid >> 2;   // 0..1  (64-row stripes)
  const int wn   = wid & 3;    // 0..3  (32-col stripes)
  const int l15  = lane & 15;
  const int l4   = lane >> 4;

  // bijective XCD-aware block swizzle (nwg = 2048, divisible by 8)
  const int nbn = M >> 7;                      // 32
  const int nwg = (N >> 7) * nbn;              // 2048
  const int cpx = nwg >> 3;
  const int swz = (blockIdx.x & 7) * cpx + (blockIdx.x >> 3);
  const int rowBase = (swz / nbn) << 7;
  const int colBase = (swz % nbn) << 7;

  // staging source pointers: thread t covers slots {L*512 + t}, L=0,1;
  // logical (row = slot>>3, c = (slot&7) ^ (row&7)); LDS dest stays linear.
  const signed char* sA[2];
  const signed char* sB[2];
#pragma unroll
  for (int L = 0; L < 2; ++L) {
    const int slot = L * 512 + tid;
    const int row  = slot >> 3;
    const int c    = (slot & 7) ^ (row & 7);
    sA[L] = qx + (size_t)(rowBase + row) * K + c * 16;
    sB[L] = qw + (size_t)(colBase + row) * K + c * 16;
  }

  signed char* A0 = lds[0];
  signed char* B0 = lds[1];
  signed char* A1 = lds[2];
  signed char* B1 = lds[3];

#define STAGE(dst, src, kt)                                  \
  do {                                                       \
    gload_lds16(src[0] + (kt) * BKB, (dst) + tid * 16);      \
    gload_lds16(src[1] + (kt) * BKB, (dst) + 8192 + tid * 16); \
  } while (0)

  // fragment-read addressing (row&7 == l15&7 since frag bases are mult of 16)
  const int ck0 = ((l4) ^ (l15 & 7)) * 16;       // ks=0 chunk offset
  const int ck1 = ((4 + l4) ^ (l15 & 7)) * 16;   // ks=1
  const int aRow0 = (wm * 64 + l15) * 128;
  const int bRow0 = (wn * 32 + l15) * 128;

  i32x4 acc[4][2] = {{{0}}};
  i32x4 af[4][2];
  i32x4 bf[2][2];

#define RDA(R, mb)                                                          \
  {                                                                         \
    _Pragma("unroll") for (int mi = 0; mi < 2; ++mi) {                      \
      af[(mb) + mi][0] = *(const i32x4*)((R) + aRow0 + ((mb) + mi) * 2048 + ck0); \
      af[(mb) + mi][1] = *(const i32x4*)((R) + aRow0 + ((mb) + mi) * 2048 + ck1); \
    }                                                                       \
  }
#define RDB(R)                                                              \
  {                                                                         \
    _Pragma("unroll") for (int nj = 0; nj < 2; ++nj) {                      \
      bf[nj][0] = *(const i32x4*)((R) + bRow0 + nj * 2048 + ck0);           \
      bf[nj][1] = *(const i32x4*)((R) + bRow0 + nj * 2048 + ck1);           \
    }                                                                       \
  }
#define MFMAH(mb)                                                           \
  {                                                                         \
    _Pragma("unroll") for (int mi = 0; mi < 2; ++mi)                        \
        _Pragma("unroll") for (int nj = 0; nj < 2; ++nj)                    \
            _Pragma("unroll") for (int ks = 0; ks < 2; ++ks)                \
                acc[(mb) + mi][nj] = __builtin_amdgcn_mfma_i32_16x16x64_i8( \
                    af[(mb) + mi][ks], bf[nj][ks], acc[(mb) + mi][nj], 0, 0, 0); \
  }

  const int T = K / BKB;  // 32 K-tiles

  // prologue: A0,B0 <- tile0 (4 loads), B1 <- tile1 (2 loads).
  // vmcnt(2): A0,B0 complete for all waves; B1 floats. Then publish barrier.
  STAGE(A0, sA, 0);
  STAGE(B0, sB, 0);
  STAGE(B1, sB, 1);
  VMCNT2();
  BARRIER();

  for (int it = 0; it < T / 2; ++it) {
    const int k1 = 2 * it + 1;
    const int k2 = (2 * it + 2 < T) ? 2 * it + 2 : T - 1;  // clamped (stale, never read)
    const int k3 = (2 * it + 3 < T) ? 2 * it + 3 : T - 1;

    // P1: read A0[mi01]+B0 (gated end-prev-P4); stage A1 <- t+1
    //     (A1's old content last read prev-P4, >=1 barrier ago).
    RDA(A0, 0); RDB(B0);
    STAGE(A1, sA, k1);
    BARRIER(); LGKM0();
    __builtin_amdgcn_s_setprio(1); MFMAH(0); __builtin_amdgcn_s_setprio(0);
    BARRIER();

    // P2: read A0[mi23]; stage B0 <- t+2 (B0 reads done in P1).
    //     GATE end-P2: vmcnt(2) leaves only P2's B0 in flight ->
    //     prev-P4's B1(t+1) and P1's A1(t+1) complete; barrier publishes for P3.
    RDA(A0, 2);
    STAGE(B0, sB, k2);
    BARRIER(); LGKM0();
    __builtin_amdgcn_s_setprio(1); MFMAH(2); __builtin_amdgcn_s_setprio(0);
    VMCNT2();
    BARRIER();

    // P3: read A1[mi01]+B1 (tile t+1); stage A0 <- t+2 (A0 reads done in P2).
    RDA(A1, 0); RDB(B1);
    STAGE(A0, sA, k2);
    BARRIER(); LGKM0();
    __builtin_amdgcn_s_setprio(1); MFMAH(0); __builtin_amdgcn_s_setprio(0);
    BARRIER();

    // P4: read A1[mi23]; stage B1 <- t+3 (B1 reads done in P3).
    //     GATE end-P4: vmcnt(2) leaves only P4's B1 in flight ->
    //     P2's B0(t+2) and P3's A0(t+2) complete; barrier publishes for next P1.
    RDA(A1, 2);
    STAGE(B1, sB, k3);
    BARRIER(); LGKM0();
    __builtin_amdgcn_s_setprio(1); MFMAH(2); __builtin_amdgcn_s_setprio(0);
    VMCNT2();
    BARRIER();
  }

  // epilogue: dequant + bias. C/D: col = lane&15, row = (lane>>4)*4 + reg
  const float dq = amax_x[0] * amax_w[0] * (1.0f / (127.0f * 127.0f));
#pragma unroll
  for (int nj = 0; nj < 2; ++nj) {
    const int col = colBase + wn * 32 + nj * 16 + l15;
    const float bv = bias[col];
#pragma unroll
    for (int mi = 0; mi < 4; ++mi) {
      const int row = rowBase + wm * 64 + mi * 16 + l4 * 4;
#pragma unroll
      for (int r = 0; r < 4; ++r)
        out[(size_t)(row + r) * M + col] = (float)acc[mi][nj][r] * dq + bv;
    }
  }
#undef STAGE
#undef RDA
#undef RDB
#undef MFMAH
}

// ---------------------------------------------------------------------------
// Launch
// ---------------------------------------------------------------------------
extern "C" void kernel_launch(void* const* d_in, const int* in_sizes, int n_in,
                              void* d_out, int out_size, void* d_ws, size_t ws_size,
                              hipStream_t stream) {
  const float* x      = (const float*)d_in[0];
  const float* w      = (const float*)d_in[1];
  const float* bias   = (const float*)d_in[2];
  const float* amax_x = (const float*)d_in[3];
  const float* amax_w = (const float*)d_in[4];
  float* out = (float*)d_out;

  const int M = in_sizes[2];                    // 4096
  const int K = in_sizes[1] / M;                // 4096
  const int N = (int)((long)in_sizes[0] / K);   // 8192

  signed char* qx = (signed char*)d_ws;         // [N,K] int8
  signed char* qw = qx + (size_t)N * K;         // [M,K] int8

  quant_i8_kernel<<<2048, 256, 0, stream>>>(x, qx, amax_x, N * (K / 4));
  quant_i8_kernel<<<2048, 256, 0, stream>>>(w, qw, amax_w, M * (K / 4));

  const int nwg = (N / 128) * (M / 128);        // 2048
  gemm_i8_4p<<<nwg, 512, 0, stream>>>(qx, qw, bias, amax_x, amax_w, out,
                                      N, M, K);
}

// Round 5
// 217.373 us; speedup vs baseline: 1.0610x; 1.0610x over previous
//
#include <hip/hip_runtime.h>

typedef __attribute__((ext_vector_type(4))) int i32x4;

// ---------------------------------------------------------------------------
// Helpers
// ---------------------------------------------------------------------------
__device__ __forceinline__ void gload_lds16(const void* g, void* l) {
  // async global->LDS, 16B/lane. LDS dest must be wave-uniform base + lane*16.
  __builtin_amdgcn_global_load_lds((const __attribute__((address_space(1))) void*)g,
                                   (__attribute__((address_space(3))) void*)l,
                                   16, 0, 0);
}

#define BARRIER() __builtin_amdgcn_s_barrier()
#define LGKM0()   asm volatile("s_waitcnt lgkmcnt(0)" ::: "memory")
#define VMCNT3()  asm volatile("s_waitcnt vmcnt(3)" ::: "memory")

// ---------------------------------------------------------------------------
// Fused quantize f32 -> int8 for both x and w (round-half-even, clamp +-127)
// ---------------------------------------------------------------------------
__global__ void quant_both_kernel(const float* __restrict__ x,
                                  const float* __restrict__ w,
                                  signed char* __restrict__ qx,
                                  signed char* __restrict__ qw,
                                  const float* __restrict__ amax_x,
                                  const float* __restrict__ amax_w,
                                  int nx4, int nw4) {
  const float sx = 127.0f / amax_x[0];
  const float sw = 127.0f / amax_w[0];
  int i = blockIdx.x * blockDim.x + threadIdx.x;
  const int stride = gridDim.x * blockDim.x;
  const int ntot = nx4 + nw4;
  for (; i < ntot; i += stride) {
    const bool isx = i < nx4;
    const float4* src = isx ? (const float4*)x : (const float4*)w;
    int* dst = isx ? (int*)qx : (int*)qw;
    const int j = isx ? i : i - nx4;
    const float s = isx ? sx : sw;
    float4 v = src[j];
    int q0 = (int)rintf(fminf(fmaxf(v.x * s, -127.0f), 127.0f));
    int q1 = (int)rintf(fminf(fmaxf(v.y * s, -127.0f), 127.0f));
    int q2 = (int)rintf(fminf(fmaxf(v.z * s, -127.0f), 127.0f));
    int q3 = (int)rintf(fminf(fmaxf(v.w * s, -127.0f), 127.0f));
    dst[j] = (q0 & 255) | ((q1 & 255) << 8) | ((q2 & 255) << 16) | ((q3 & 255) << 24);
  }
}

// ---------------------------------------------------------------------------
// 256x128-tile int8 GEMM, BK=64, one phase per K-tile, 2 blocks/CU.
// out[N,M] = dequant(qx[N,K] . qw[M,K]^T) + bias
// 512 thr = 8 waves (2M x 4N), per-wave 128x32, mfma_i32_16x16x64_i8.
// LDS = dbuf x (A[256][64] + B[128][64]) = 48 KiB -> 2 blocks/CU, 4 waves/SIMD.
// Phase(t): {RD A[p],B[p]; lgkm0; BARRIER(publish reads); STAGE t+2 -> [p];
//            16 MFMA; vmcnt(3)(drain t+1, keep t+2); BARRIER(publish t+1)}.
// Swizzle (64B rows, 4 chunks): chunk' = chunk ^ ((row>>1)&3) — covers all 8
// 16B bank-groups across 16-row fragment reads (2-way = free). Applied to
// global SOURCE on staging (LDS dest linear, rule #21) and to ds_read addr.
// ---------------------------------------------------------------------------
__global__ __launch_bounds__(512, 4) void gemm_i8_bk64(
    const signed char* __restrict__ qx,   // [N,K]
    const signed char* __restrict__ qw,   // [M,K]
    const float* __restrict__ bias,       // [M]
    const float* __restrict__ amax_x,
    const float* __restrict__ amax_w,
    float* __restrict__ out,              // [N,M]
    int N, int M, int K) {
  constexpr int BKB = 64;  // K bytes per tile

  // A0[16K] A1[16K] B0[8K] B1[8K]
  __shared__ signed char lds[49152];

  const int tid  = threadIdx.x;
  const int lane = tid & 63;
  const int wid  = tid >> 6;
  const int wm   = wid >> 2;   // 0..1  (128-row stripes of N)
  const int wn   = wid & 3;    // 0..3  (32-col stripes of M)
  const int l15  = lane & 15;
  const int l4   = lane >> 4;

  // bijective XCD-aware block swizzle (nwg = 1024, divisible by 8)
  const int nbn = M >> 7;                      // 32
  const int nwg = (N >> 8) * nbn;              // 1024
  const int cpx = nwg >> 3;
  const int swz = (blockIdx.x & 7) * cpx + (blockIdx.x >> 3);
  const int rowBase = (swz / nbn) << 8;        // 256-row tiles
  const int colBase = (swz % nbn) << 7;        // 128-col tiles

  // staging sources. A tile = 256 rows x 4 chunks = 1024 slots (2 units);
  // B tile = 128 rows x 4 chunks = 512 slots (1 unit). LDS dest linear.
  const signed char* srcA[2];
#pragma unroll
  for (int L = 0; L < 2; ++L) {
    const int slot = L * 512 + tid;
    const int row  = slot >> 2;
    const int c    = (slot & 3) ^ ((row >> 1) & 3);
    srcA[L] = qx + (size_t)(rowBase + row) * K + c * 16;
  }
  const int rowB = tid >> 2;
  const int cB   = (tid & 3) ^ ((rowB >> 1) & 3);
  const signed char* srcB = qw + (size_t)(colBase + rowB) * K + cB * 16;

  signed char* A[2] = {lds, lds + 16384};
  signed char* B[2] = {lds + 32768, lds + 40960};

#define STAGE(p, kt)                                                   \
  do {                                                                 \
    gload_lds16(srcA[0] + (kt) * BKB, A[p] + tid * 16);                \
    gload_lds16(srcA[1] + (kt) * BKB, A[p] + 8192 + tid * 16);         \
    gload_lds16(srcB + (kt) * BKB, B[p] + tid * 16);                   \
  } while (0)

  i32x4 acc[8][2] = {{{0}}};
  i32x4 af[8];
  i32x4 bf[2];

  // fragment read offsets (row-dependent swizzle folded per-lane)
  int offA[8], offB[2];
#pragma unroll
  for (int mi = 0; mi < 8; ++mi) {
    const int r = wm * 128 + mi * 16 + l15;
    offA[mi] = r * 64 + ((l4 ^ ((r >> 1) & 3)) * 16);
  }
#pragma unroll
  for (int nj = 0; nj < 2; ++nj) {
    const int r = wn * 32 + nj * 16 + l15;
    offB[nj] = r * 64 + ((l4 ^ ((r >> 1) & 3)) * 16);
  }

#define PHASE(p, ktStage)                                                     \
  do {                                                                        \
    _Pragma("unroll") for (int mi = 0; mi < 8; ++mi)                          \
        af[mi] = *(const i32x4*)(A[p] + offA[mi]);                            \
    _Pragma("unroll") for (int nj = 0; nj < 2; ++nj)                          \
        bf[nj] = *(const i32x4*)(B[p] + offB[nj]);                            \
    LGKM0();                                                                  \
    BARRIER(); /* all waves' reads of [p] complete */                         \
    STAGE(p, ktStage);                                                        \
    __builtin_amdgcn_s_setprio(1);                                            \
    _Pragma("unroll") for (int mi = 0; mi < 8; ++mi)                          \
        _Pragma("unroll") for (int nj = 0; nj < 2; ++nj)                      \
            acc[mi][nj] = __builtin_amdgcn_mfma_i32_16x16x64_i8(              \
                af[mi], bf[nj], acc[mi][nj], 0, 0, 0);                        \
    __builtin_amdgcn_s_setprio(0);                                            \
    VMCNT3(); /* drain tile t+1's 3 loads; keep t+2's in flight */            \
    BARRIER(); /* publish tile t+1 */                                         \
  } while (0)

  const int T = K / BKB;  // 64 K-tiles

  // prologue: stage t0 -> [0], t1 -> [1]; drain t0 (vmcnt(3)); publish.
  STAGE(0, 0);
  STAGE(1, 1);
  VMCNT3();
  BARRIER();

  for (int it = 0; it < T / 2; ++it) {
    const int k2 = (2 * it + 2 < T) ? 2 * it + 2 : T - 1;  // clamped, never read
    const int k3 = (2 * it + 3 < T) ? 2 * it + 3 : T - 1;
    PHASE(0, k2);
    PHASE(1, k3);
  }

  // epilogue: dequant + bias. C/D: col = lane&15, row = (lane>>4)*4 + reg
  const float dq = amax_x[0] * amax_w[0] * (1.0f / (127.0f * 127.0f));
#pragma unroll
  for (int nj = 0; nj < 2; ++nj) {
    const int col = colBase + wn * 32 + nj * 16 + l15;
    const float bv = bias[col];
#pragma unroll
    for (int mi = 0; mi < 8; ++mi) {
      const int row = rowBase + wm * 128 + mi * 16 + l4 * 4;
#pragma unroll
      for (int r = 0; r < 4; ++r)
        out[(size_t)(row + r) * M + col] = (float)acc[mi][nj][r] * dq + bv;
    }
  }
#undef STAGE
#undef PHASE
}

// ---------------------------------------------------------------------------
// Launch
// ---------------------------------------------------------------------------
extern "C" void kernel_launch(void* const* d_in, const int* in_sizes, int n_in,
                              void* d_out, int out_size, void* d_ws, size_t ws_size,
                              hipStream_t stream) {
  const float* x      = (const float*)d_in[0];
  const float* w      = (const float*)d_in[1];
  const float* bias   = (const float*)d_in[2];
  const float* amax_x = (const float*)d_in[3];
  const float* amax_w = (const float*)d_in[4];
  float* out = (float*)d_out;

  const int M = in_sizes[2];                    // 4096
  const int K = in_sizes[1] / M;                // 4096
  const int N = (int)((long)in_sizes[0] / K);   // 8192

  signed char* qx = (signed char*)d_ws;         // [N,K] int8
  signed char* qw = qx + (size_t)N * K;         // [M,K] int8

  const int nx4 = N * (K / 4);
  const int nw4 = M * (K / 4);
  quant_both_kernel<<<2048, 256, 0, stream>>>(x, w, qx, qw, amax_x, amax_w,
                                              nx4, nw4);

  const int nwg = (N / 256) * (M / 128);        // 1024
  gemm_i8_bk64<<<nwg, 512, 0, stream>>>(qx, qw, bias, amax_x, amax_w, out,
                                        N, M, K);
}

// Round 6
// 191.887 us; speedup vs baseline: 1.2019x; 1.1328x over previous
//
#include <hip/hip_runtime.h>

typedef __attribute__((ext_vector_type(4))) int i32x4;

// ---------------------------------------------------------------------------
// Helpers
// ---------------------------------------------------------------------------
__device__ __forceinline__ void gload_lds16(const void* g, void* l) {
  // async global->LDS, 16B/lane. LDS dest must be wave-uniform base + lane*16.
  __builtin_amdgcn_global_load_lds((const __attribute__((address_space(1))) void*)g,
                                   (__attribute__((address_space(3))) void*)l,
                                   16, 0, 0);
}

#define BARRIER() __builtin_amdgcn_s_barrier()
#define VMCNT4()  asm volatile("s_waitcnt vmcnt(4)" ::: "memory")
#define SCHED0()  __builtin_amdgcn_sched_barrier(0)

// ---------------------------------------------------------------------------
// Fused quantize f32 -> int8 for both x and w (round-half-even, clamp +-127)
// ---------------------------------------------------------------------------
__global__ void quant_both_kernel(const float* __restrict__ x,
                                  const float* __restrict__ w,
                                  signed char* __restrict__ qx,
                                  signed char* __restrict__ qw,
                                  const float* __restrict__ amax_x,
                                  const float* __restrict__ amax_w,
                                  int nx4, int nw4) {
  const float sx = 127.0f / amax_x[0];
  const float sw = 127.0f / amax_w[0];
  int i = blockIdx.x * blockDim.x + threadIdx.x;
  const int stride = gridDim.x * blockDim.x;
  const int ntot = nx4 + nw4;
  for (; i < ntot; i += stride) {
    const bool isx = i < nx4;
    const float4* src = isx ? (const float4*)x : (const float4*)w;
    int* dst = isx ? (int*)qx : (int*)qw;
    const int j = isx ? i : i - nx4;
    const float s = isx ? sx : sw;
    float4 v = src[j];
    int q0 = (int)rintf(fminf(fmaxf(v.x * s, -127.0f), 127.0f));
    int q1 = (int)rintf(fminf(fmaxf(v.y * s, -127.0f), 127.0f));
    int q2 = (int)rintf(fminf(fmaxf(v.z * s, -127.0f), 127.0f));
    int q3 = (int)rintf(fminf(fmaxf(v.w * s, -127.0f), 127.0f));
    dst[j] = (q0 & 255) | ((q1 & 255) << 8) | ((q2 & 255) << 16) | ((q3 & 255) << 24);
  }
}

// ---------------------------------------------------------------------------
// 256x256 8-phase int8 GEMM (R3 structure) + register read-ahead pipelining:
// fragment reads are issued 1-2 phases before their MFMA (double register
// sets afA/afB, bfA/bfB), so the LDS drain overlaps earlier phases' MFMA.
// No explicit lgkmcnt(0): reads are C-level, compiler emits per-use waits.
// Gates/staging/swizzle identical to the verified round-3 kernel.
// out[N,M] = dequant(qx[N,K] . qw[M,K]^T) + bias
// 512 thr = 8 waves (2M x 4N), per-wave 128x64, mfma_i32_16x16x64_i8,
// BK=128 int8 (2 k-subtiles of 64), LDS 2dbuf x (A,B) x [256][128B] = 128 KiB.
// Swizzle: 16B-chunk' = chunk ^ (row&7); inverse on global SOURCE (rule #21),
// forward on ds_read address. Measured 0 bank conflicts.
// ---------------------------------------------------------------------------
__global__ __launch_bounds__(512, 2) void gemm_i8_8p(
    const signed char* __restrict__ qx,   // [N,K]
    const signed char* __restrict__ qw,   // [M,K]
    const float* __restrict__ bias,       // [M]
    const float* __restrict__ amax_x,
    const float* __restrict__ amax_w,
    float* __restrict__ out,              // [N,M]
    int N, int M, int K) {
  constexpr int BKB = 128;  // K bytes per tile

  __shared__ signed char lds[4][256 * 128];  // [A0,B0,A1,B1], 32 KiB each

  const int tid  = threadIdx.x;
  const int lane = tid & 63;
  const int wid  = tid >> 6;
  const int wm   = wid >> 2;   // 0..1
  const int wn   = wid & 3;    // 0..3
  const int l15  = lane & 15;
  const int l4   = lane >> 4;

  // bijective XCD-aware block swizzle (nwg = 512, divisible by 8)
  const int nbn = M >> 8;                      // 16
  const int nwg = (N >> 8) * nbn;              // 512
  const int cpx = nwg >> 3;
  const int swz = (blockIdx.x & 7) * cpx + (blockIdx.x >> 3);
  const int rowBase = (swz / nbn) << 8;
  const int colBase = (swz % nbn) << 8;

  // staging source pointers: thread t covers slots {h*1024 + L*512 + t};
  // logical (row = slot>>3, c = (slot&7) ^ (row&7)); LDS dest stays linear.
  const signed char* sA[2][2];
  const signed char* sB[2][2];
#pragma unroll
  for (int h = 0; h < 2; ++h)
#pragma unroll
    for (int L = 0; L < 2; ++L) {
      const int slot = h * 1024 + L * 512 + tid;
      const int row  = slot >> 3;
      const int c    = (slot & 7) ^ (row & 7);
      sA[h][L] = qx + (size_t)(rowBase + row) * K + c * 16;
      sB[h][L] = qw + (size_t)(colBase + row) * K + c * 16;
    }

  signed char* A0 = lds[0];
  signed char* B0 = lds[1];
  signed char* A1 = lds[2];
  signed char* B1 = lds[3];

#define STAGE(dst, src, h, kt)                                             \
  do {                                                                     \
    gload_lds16(src[h][0] + (kt) * BKB, (dst) + (h)*16384 + tid * 16);     \
    gload_lds16(src[h][1] + (kt) * BKB, (dst) + (h)*16384 + 8192 + tid * 16); \
  } while (0)

  // fragment-read addressing (row&7 == l15&7 since frag bases are mult of 16)
  const int ck0 = ((l4) ^ (l15 & 7)) * 16;       // ks=0 chunk offset
  const int ck1 = ((4 + l4) ^ (l15 & 7)) * 16;   // ks=1
  const int aRow0 = (wm * 128 + l15) * 128;
  const int bRow0 = (wn * 64 + l15) * 128;

  i32x4 acc[8][4] = {{{0}}};
  i32x4 afA[4][2], afB[4][2];   // A fragment double-buffer (M0 / M1 halves)
  i32x4 bfA[2][2], bfB[2][2];   // B fragment double-buffer (N0 / N1 halves)

#define RD_A(DST, R, mb)                                                    \
  {                                                                         \
    _Pragma("unroll") for (int mi = 0; mi < 4; ++mi) {                      \
      DST[mi][0] = *(const i32x4*)((R) + aRow0 + ((mb) + mi) * 2048 + ck0); \
      DST[mi][1] = *(const i32x4*)((R) + aRow0 + ((mb) + mi) * 2048 + ck1); \
    }                                                                       \
  }
#define RD_B(DST, R, nb)                                                    \
  {                                                                         \
    _Pragma("unroll") for (int nj = 0; nj < 2; ++nj) {                      \
      DST[nj][0] = *(const i32x4*)((R) + bRow0 + ((nb) + nj) * 2048 + ck0); \
      DST[nj][1] = *(const i32x4*)((R) + bRow0 + ((nb) + nj) * 2048 + ck1); \
    }                                                                       \
  }
#define MFMAQ(mb, nb, AF, BF)                                               \
  {                                                                         \
    __builtin_amdgcn_s_setprio(1);                                          \
    _Pragma("unroll") for (int mi = 0; mi < 4; ++mi)                        \
        _Pragma("unroll") for (int nj = 0; nj < 2; ++nj)                    \
            _Pragma("unroll") for (int ks = 0; ks < 2; ++ks)                \
                acc[(mb) + mi][(nb) + nj] = __builtin_amdgcn_mfma_i32_16x16x64_i8( \
                    AF[mi][ks], BF[nj][ks], acc[(mb) + mi][(nb) + nj], 0, 0, 0);   \
    __builtin_amdgcn_s_setprio(0);                                          \
  }

  const int T = K / BKB;  // 32 K-tiles

  // prologue: tile0 -> A0/B0 (8 loads), tile1's B -> B1 (4 loads).
  // vmcnt(4): every wave's A0/B0 loads complete; B1 floats. Barrier publishes.
  STAGE(B0, sB, 0, 0); STAGE(B0, sB, 1, 0);
  STAGE(A0, sA, 0, 0); STAGE(A0, sA, 1, 0);
  STAGE(B1, sB, 0, 1); STAGE(B1, sB, 1, 1);
  VMCNT4();
  BARRIER();

  for (int it = 0; it < T / 2; ++it) {
    const int k1 = 2 * it + 1;
    const int k2 = (2 * it + 2 < T) ? 2 * it + 2 : T - 1;  // clamped (stale, never read)
    const int k3 = (2 * it + 3 < T) ? 2 * it + 3 : T - 1;

    // P1: issue ALL legal reads from A0/B0 window: M0, N0, N1 (16 reads).
    //     MFMA(M0,N0). Stage A1h0 <- t+1.
    RD_A(afA, A0, 0); RD_B(bfA, B0, 0); RD_B(bfB, B0, 2);
    STAGE(A1, sA, 0, k1);
    SCHED0();
    BARRIER();
    MFMAQ(0, 0, afA, bfA);
    BARRIER();

    // P2: issue M1 reads (8). MFMA(M0,N1) — operands issued in P1,
    //     drained under P1's MFMA. Stage A1h1 <- t+1.
    RD_A(afB, A0, 4);
    STAGE(A1, sA, 1, k1);
    SCHED0();
    BARRIER();
    MFMAQ(0, 2, afA, bfB);
    BARRIER();

    // P3: no reads. MFMA(M1,N0) — afB issued P2-top. Stage B0h0 <- t+2
    //     (all B0 reads were issued P1-top and consumed by P1/P2 MFMAs).
    STAGE(B0, sB, 0, k2);
    BARRIER();
    MFMAQ(4, 0, afB, bfA);
    BARRIER();

    // P4: no reads. MFMA(M1,N1). Stage B0h1 <- t+2.
    //     GATE tile t+1: vmcnt(4) leaves only P3/P4's B0 loads in flight ->
    //     A1(t+1, P1/P2) and B1(t+1, prev P7/P8) complete; barrier publishes.
    STAGE(B0, sB, 1, k2);
    BARRIER();
    MFMAQ(4, 2, afB, bfB);
    VMCNT4();
    BARRIER();

    // P5-P8: mirror on A1/B1 (tile t+1), staging A0 <- t+2, B1 <- t+3.
    RD_A(afA, A1, 0); RD_B(bfA, B1, 0); RD_B(bfB, B1, 2);
    STAGE(A0, sA, 0, k2);
    SCHED0();
    BARRIER();
    MFMAQ(0, 0, afA, bfA);
    BARRIER();

    RD_A(afB, A1, 4);
    STAGE(A0, sA, 1, k2);
    SCHED0();
    BARRIER();
    MFMAQ(0, 2, afA, bfB);
    BARRIER();

    STAGE(B1, sB, 0, k3);
    BARRIER();
    MFMAQ(4, 0, afB, bfA);
    BARRIER();

    STAGE(B1, sB, 1, k3);
    BARRIER();
    MFMAQ(4, 2, afB, bfB);
    VMCNT4();
    BARRIER();
  }

  // epilogue: dequant + bias. C/D: col = lane&15, row = (lane>>4)*4 + reg
  const float dq = amax_x[0] * amax_w[0] * (1.0f / (127.0f * 127.0f));
#pragma unroll
  for (int nj = 0; nj < 4; ++nj) {
    const int col = colBase + wn * 64 + nj * 16 + l15;
    const float bv = bias[col];
#pragma unroll
    for (int mi = 0; mi < 8; ++mi) {
      const int row = rowBase + wm * 128 + mi * 16 + l4 * 4;
#pragma unroll
      for (int r = 0; r < 4; ++r)
        out[(size_t)(row + r) * M + col] = (float)acc[mi][nj][r] * dq + bv;
    }
  }
#undef STAGE
#undef RD_A
#undef RD_B
#undef MFMAQ
}

// ---------------------------------------------------------------------------
// Launch
// ---------------------------------------------------------------------------
extern "C" void kernel_launch(void* const* d_in, const int* in_sizes, int n_in,
                              void* d_out, int out_size, void* d_ws, size_t ws_size,
                              hipStream_t stream) {
  const float* x      = (const float*)d_in[0];
  const float* w      = (const float*)d_in[1];
  const float* bias   = (const float*)d_in[2];
  const float* amax_x = (const float*)d_in[3];
  const float* amax_w = (const float*)d_in[4];
  float* out = (float*)d_out;

  const int M = in_sizes[2];                    // 4096
  const int K = in_sizes[1] / M;                // 4096
  const int N = (int)((long)in_sizes[0] / K);   // 8192

  signed char* qx = (signed char*)d_ws;         // [N,K] int8
  signed char* qw = qx + (size_t)N * K;         // [M,K] int8

  const int nx4 = N * (K / 4);
  const int nw4 = M * (K / 4);
  quant_both_kernel<<<2048, 256, 0, stream>>>(x, w, qx, qw, amax_x, amax_w,
                                              nx4, nw4);

  const int nwg = (N / 256) * (M / 256);        // 512
  gemm_i8_8p<<<nwg, 512, 0, stream>>>(qx, qw, bias, amax_x, amax_w, out,
                                      N, M, K);
}